// Round 1
// baseline (1000.433 us; speedup 1.0000x reference)
//
#include <hip/hip_runtime.h>
#include <math.h>

// ---------------------------------------------------------------------------
// ObservationFusionModule: fully fused, f32 (correctness-first round).
// Algebra:
//   qk   = (Wk^T Wq) h + Wk^T bq
//   qk2  = w2^T qk
//   x2_s = relu(w1 @ relu(w0*log1p(st_s)+b0) + b1)
//   score_s    = (qk.obs_s + qk2.x2_s + qk.b2 + h.(Wq^T bk) + bq.bk)/16 + mask
//   score_null = (h.(Wq^T nk) + bq.nk)/16
//   softmax online over s; obar = sum w_s obs_s ; x2b = sum w_s x2_s ; Wbar, w4
//   fused = Wv obar + (Wv w2) x2b + Wbar*(Wv b2 + bv) + w4*nv
//   gate  = sigmoid(Wg1 h + Wg2 fused + bg) * any_real
//   out   = h + gate * LN(fused)
// ---------------------------------------------------------------------------

constexpr int Tr = 16; // rows per block

// ws layout (float indices); ws[0] holds the valid-dtype mode flag (int)
constexpr int OFF_MTQK = 16;                    // [256][256]  MT[b][a] = (Wk^T Wq)[a][b]
constexpr int OFF_MTV  = OFF_MTQK + 256 * 256;  // [256][256]  MT[i][o] = Wv[o][i]
constexpr int OFF_MTG1 = OFF_MTV + 256 * 256;   // [256][256]  MT[i][o] = Wg[o][i]
constexpr int OFF_MTG2 = OFF_MTG1 + 256 * 256;  // [256][256]  MT[i][o] = Wg[o][256+i]
constexpr int OFF_MTW1 = OFF_MTG2 + 256 * 256;  // [128][128]  MT[i][o] = w1[o][i]
constexpr int OFF_MTV2 = OFF_MTW1 + 128 * 128;  // [128][256]  MT[w][o] = (Wv@w2)[o][w]
constexpr int OFF_BQK  = OFF_MTV2 + 128 * 256;  // [256] Wk^T bq
constexpr int OFF_NBK  = OFF_BQK + 256;         // [256] Wq^T bk
constexpr int OFF_NQ   = OFF_NBK + 256;         // [256] Wq^T null_key
constexpr int OFF_VB2P = OFF_NQ + 256;          // [256] Wv b2 + bv
constexpr int OFF_SCC  = OFF_VB2P + 256;        // [0]=bq.bk [1]=bq.nk

__device__ __forceinline__ float4 ld4(const float* p) { return *reinterpret_cast<const float4*>(p); }
__device__ __forceinline__ void st4(float* p, const float4 v) { *reinterpret_cast<float4*>(p) = v; }

// generic LDS-A x global-B matvec accumulator. threads = (MM/RT)*(NN/4) = 256.
template <int MM, int KK, int NN, int RT>
__device__ __forceinline__ void mv_acc(const float* __restrict__ A, const float* __restrict__ B,
                                       float* __restrict__ acc) {
  const int t = threadIdx.x;
  const int tcol = t % (NN / 4);
  const int trg = t / (NN / 4);
  const float* __restrict__ Bp = B + tcol * 4;
  const float* __restrict__ Ap = A + trg * RT * KK;
#pragma unroll 2
  for (int i0 = 0; i0 < KK; i0 += 4) {
    float4 av[RT];
#pragma unroll
    for (int rr = 0; rr < RT; ++rr) av[rr] = ld4(Ap + rr * KK + i0);
#pragma unroll
    for (int j = 0; j < 4; ++j) {
      const float4 w = ld4(Bp + (i0 + j) * NN);
#pragma unroll
      for (int rr = 0; rr < RT; ++rr) {
        const float a = (j == 0) ? av[rr].x : (j == 1) ? av[rr].y : (j == 2) ? av[rr].z : av[rr].w;
        acc[rr * 4 + 0] = fmaf(a, w.x, acc[rr * 4 + 0]);
        acc[rr * 4 + 1] = fmaf(a, w.y, acc[rr * 4 + 1]);
        acc[rr * 4 + 2] = fmaf(a, w.z, acc[rr * 4 + 2]);
        acc[rr * 4 + 3] = fmaf(a, w.w, acc[rr * 4 + 3]);
      }
    }
  }
}

// mlp first layer fused: A(r,i) = relu(w0[i]*x0[r]+b0[i]); threads = (MM/RT)*(NN/4)
template <int MM, int KK, int NN, int RT>
__device__ __forceinline__ void mv_mlp(const float* __restrict__ x0s, const float* __restrict__ w0,
                                       const float* __restrict__ b0, const float* __restrict__ B,
                                       float* __restrict__ acc) {
  const int t = threadIdx.x;
  const int tcol = t % (NN / 4);
  const int trg = t / (NN / 4);
  float x0r[RT];
#pragma unroll
  for (int rr = 0; rr < RT; ++rr) x0r[rr] = x0s[trg * RT + rr];
  const float* __restrict__ Bp = B + tcol * 4;
#pragma unroll 2
  for (int i0 = 0; i0 < KK; i0 += 4) {
    const float4 w0v = ld4(w0 + i0);
    const float4 b0v = ld4(b0 + i0);
#pragma unroll
    for (int j = 0; j < 4; ++j) {
      const float w0j = (j == 0) ? w0v.x : (j == 1) ? w0v.y : (j == 2) ? w0v.z : w0v.w;
      const float b0j = (j == 0) ? b0v.x : (j == 1) ? b0v.y : (j == 2) ? b0v.z : b0v.w;
      const float4 w = ld4(Bp + (i0 + j) * NN);
#pragma unroll
      for (int rr = 0; rr < RT; ++rr) {
        const float a = fmaxf(fmaf(w0j, x0r[rr], b0j), 0.f);
        acc[rr * 4 + 0] = fmaf(a, w.x, acc[rr * 4 + 0]);
        acc[rr * 4 + 1] = fmaf(a, w.y, acc[rr * 4 + 1]);
        acc[rr * 4 + 2] = fmaf(a, w.z, acc[rr * 4 + 2]);
        acc[rr * 4 + 3] = fmaf(a, w.w, acc[rr * 4 + 3]);
      }
    }
  }
}

// --- detect dtype of valid_stack (bool arrays can arrive as i32/u8/f32) ----
__global__ void k_flag(const unsigned int* __restrict__ v, int nwords, int* __restrict__ flag_out) {
  __shared__ int viol;
  if (threadIdx.x == 0) viol = 0;
  __syncthreads();
  int my = 0;
  for (int i = threadIdx.x; i < nwords; i += blockDim.x) {
    const unsigned int w = v[i];
    if (w > 1u) my |= 1;
    if (((w & 0xFFu) > 1u) || (((w >> 8) & 0xFFu) > 1u) || (((w >> 16) & 0xFFu) > 1u) ||
        ((w >> 24) > 1u))
      my |= 2;
  }
  atomicOr(&viol, my);
  __syncthreads();
  if (threadIdx.x == 0) {
    const int vv = viol;
    *flag_out = ((vv & 1) == 0) ? 0 : (((vv & 2) == 0) ? 1 : 2);  // 0=i32 1=u8 2=f32
  }
}

// --- weight prep: fused/transposed matrices into ws ------------------------
__global__ void k_prep(const float* __restrict__ Wq, const float* __restrict__ bq,
                       const float* __restrict__ Wk, const float* __restrict__ bk,
                       const float* __restrict__ Wv, const float* __restrict__ bv,
                       const float* __restrict__ nk, const float* __restrict__ w1,
                       const float* __restrict__ w2, const float* __restrict__ b2,
                       const float* __restrict__ Wg, float* __restrict__ W) {
  const int b = blockIdx.x;
  const int t = threadIdx.x;
  if (b < 256) {  // MT_qk[b][t] = sum_o Wk[o][t]*Wq[o][b]
    float acc = 0.f;
    for (int o = 0; o < 256; ++o) acc = fmaf(Wk[o * 256 + t], Wq[o * 256 + b], acc);
    W[OFF_MTQK + b * 256 + t] = acc;
  } else if (b < 512) {  // MT_v[i][o] = Wv[o][i]
    const int i = b - 256;
    W[OFF_MTV + i * 256 + t] = Wv[t * 256 + i];
  } else if (b < 768) {  // MT_g1/g2
    const int i = b - 512;
    W[OFF_MTG1 + i * 256 + t] = Wg[t * 512 + i];
    W[OFF_MTG2 + i * 256 + t] = Wg[t * 512 + 256 + i];
  } else if (b < 896) {  // MT_w1[i][o] = w1[o][i]
    const int i = b - 768;
    if (t < 128) W[OFF_MTW1 + i * 128 + t] = w1[t * 128 + i];
  } else if (b < 1024) {  // MT_v2[w][o] = sum_h Wv[o][h]*w2[h][w]
    const int wi = b - 896;
    float acc = 0.f;
    for (int hh = 0; hh < 256; ++hh) acc = fmaf(Wv[t * 256 + hh], w2[hh * 128 + wi], acc);
    W[OFF_MTV2 + wi * 256 + t] = acc;
  } else {  // vectors + scalars
    float a1 = 0.f, a2 = 0.f, a3 = 0.f, a4 = 0.f;
    for (int o = 0; o < 256; ++o) {
      a1 = fmaf(Wq[o * 256 + t], bk[o], a1);
      a2 = fmaf(Wq[o * 256 + t], nk[o], a2);
      a3 = fmaf(Wk[o * 256 + t], bq[o], a3);
    }
    for (int hh = 0; hh < 256; ++hh) a4 = fmaf(Wv[t * 256 + hh], b2[hh], a4);
    W[OFF_NBK + t] = a1;
    W[OFF_NQ + t] = a2;
    W[OFF_BQK + t] = a3;
    W[OFF_VB2P + t] = a4 + bv[t];
    if (t == 0) {
      float c1 = 0.f, c2 = 0.f;
      for (int o = 0; o < 256; ++o) {
        c1 = fmaf(bq[o], bk[o], c1);
        c2 = fmaf(bq[o], nk[o], c2);
      }
      W[OFF_SCC] = c1;
      W[OFF_SCC + 1] = c2;
    }
  }
}

// --- main fused kernel ------------------------------------------------------
__launch_bounds__(256) __global__
void k_main(const float* __restrict__ h, const float* __restrict__ obs,
            const float* __restrict__ stal, const void* __restrict__ valid,
            const float* __restrict__ w0, const float* __restrict__ b0,
            const float* __restrict__ b1, const float* __restrict__ w2,
            const float* __restrict__ b2, const float* __restrict__ bg,
            const float* __restrict__ lnw, const float* __restrict__ lnb,
            const float* __restrict__ nv, const float* __restrict__ W,
            const int* __restrict__ flagp, float* __restrict__ out) {
  extern __shared__ float sm[];
  float* s_h = sm;             // [16][256] alive whole kernel
  float* s_qk = sm + 4096;     // [16][256] qk -> later fused
  float* s_x2 = sm + 8192;     // [64][128] x2 -> later obar[16][256]+x2b[16][128] -> gate[16][256]
  float* s_qk2 = sm + 16384;   // [16][128]
  float* s_x0 = sm + 18432;    // [64]
  float* s_sc = sm + 18496;    // [16][12]: mask0..3, sbk, snull, sb2, anyreal, wbar, w4, mu, inv
  const int t = threadIdx.x;
  const int row0 = blockIdx.x * Tr;
  const int mode = *flagp;

  // ---- ph0: stage h; mask/x0/any_real -------------------------------------
#pragma unroll
  for (int i = 0; i < Tr; ++i) s_h[i * 256 + t] = h[(row0 + i) * 256 + t];
  if (t < 64) {
    const int r = t >> 2, s = t & 3;
    const int idx = (row0 + r) * 4 + s;
    bool vb;
    if (mode == 0) vb = ((const int*)valid)[idx] != 0;
    else if (mode == 1) vb = ((const unsigned char*)valid)[idx] != 0;
    else vb = ((const float*)valid)[idx] != 0.f;
    s_sc[r * 12 + s] = vb ? 0.f : -5.f;
    s_x0[t] = log1pf(stal[idx]);
  } else if (t < 80) {
    const int r = t - 64;
    const int base = (row0 + r) * 4;
    bool any = false;
    for (int s = 0; s < 4; ++s) {
      bool vb;
      if (mode == 0) vb = ((const int*)valid)[base + s] != 0;
      else if (mode == 1) vb = ((const unsigned char*)valid)[base + s] != 0;
      else vb = ((const float*)valid)[base + s] != 0.f;
      any |= vb;
    }
    s_sc[r * 12 + 7] = any ? 1.f : 0.f;
  }
  __syncthreads();

  // ---- ph1: qk = MT_qk^T h + bqk ------------------------------------------
  {
    float acc[16];
#pragma unroll
    for (int i = 0; i < 16; ++i) acc[i] = 0.f;
    mv_acc<16, 256, 256, 4>(s_h, W + OFF_MTQK, acc);
    const int tcol = t & 63, trg = t >> 6;
#pragma unroll
    for (int rr = 0; rr < 4; ++rr) {
      const int r = trg * 4 + rr;
#pragma unroll
      for (int c = 0; c < 4; ++c)
        s_qk[r * 256 + tcol * 4 + c] = acc[rr * 4 + c] + W[OFF_BQK + tcol * 4 + c];
    }
  }
  __syncthreads();

  // ---- ph1b: per-row score constants (48 threads) + ph2: mlp x2 (all) ----
  if (t < 48) {
    const int r = t & 15, which = t >> 4;
    const float* a = (which == 2) ? (s_qk + r * 256) : (s_h + r * 256);
    const float* vec = (which == 0) ? (W + OFF_NBK) : (which == 1) ? (W + OFF_NQ) : b2;
    float acc = 0.f;
    for (int c = 0; c < 256; ++c) acc = fmaf(a[c], vec[c], acc);
    if (which == 0) acc += W[OFF_SCC];
    if (which == 1) acc += W[OFF_SCC + 1];
    s_sc[r * 12 + 4 + which] = acc;
  }
  {
    float acc[32];
#pragma unroll
    for (int i = 0; i < 32; ++i) acc[i] = 0.f;
    mv_mlp<64, 128, 128, 8>(s_x0, w0, b0, W + OFF_MTW1, acc);
    const int tcol = t & 31, trg = t >> 5;
#pragma unroll
    for (int rr = 0; rr < 8; ++rr) {
      const int p = trg * 8 + rr;
#pragma unroll
      for (int c = 0; c < 4; ++c)
        s_x2[p * 128 + tcol * 4 + c] = fmaxf(acc[rr * 4 + c] + b1[tcol * 4 + c], 0.f);
    }
  }
  __syncthreads();

  // ---- ph3: qk2 = w2^T qk --------------------------------------------------
  {
    float acc[8];
#pragma unroll
    for (int i = 0; i < 8; ++i) acc[i] = 0.f;
    mv_acc<16, 256, 128, 2>(s_qk, w2, acc);
    const int tcol = t & 31, trg = t >> 5;
#pragma unroll
    for (int rr = 0; rr < 2; ++rr) {
      const int r = trg * 2 + rr;
#pragma unroll
      for (int c = 0; c < 4; ++c) s_qk2[r * 128 + tcol * 4 + c] = acc[rr * 4 + c];
    }
  }
  __syncthreads();

  // ---- ph4: stream obs once; online softmax; accumulate obar/x2b in regs --
  {
    const int wv = t >> 6, lane = t & 63;
    float ob[4][4], xbr[4][2], wbar[4], w4r[4];
#pragma unroll
    for (int rr = 0; rr < 4; ++rr) {
      const int r = wv * 4 + rr;
      const int l = row0 + r;
      const float4 qv = ld4(s_qk + r * 256 + lane * 4);
      const float q2a = s_qk2[r * 128 + lane * 2];
      const float q2b = s_qk2[r * 128 + lane * 2 + 1];
      const float sb2 = s_sc[r * 12 + 6];
      const float sbk = s_sc[r * 12 + 4];
      float m = -INFINITY, d4 = 0.f;
      float o0 = 0.f, o1 = 0.f, o2 = 0.f, o3 = 0.f, xa0 = 0.f, xa1 = 0.f;
#pragma unroll
      for (int s = 0; s < 4; ++s) {
        const float4 ov = ld4(obs + (l * 4 + s) * 256 + lane * 4);
        const float xa = s_x2[(r * 4 + s) * 128 + lane * 2];
        const float xc = s_x2[(r * 4 + s) * 128 + lane * 2 + 1];
        float part = qv.x * ov.x + qv.y * ov.y + qv.z * ov.z + qv.w * ov.w + q2a * xa + q2b * xc;
        part += __shfl_xor(part, 32, 64);
        part += __shfl_xor(part, 16, 64);
        part += __shfl_xor(part, 8, 64);
        part += __shfl_xor(part, 4, 64);
        part += __shfl_xor(part, 2, 64);
        part += __shfl_xor(part, 1, 64);
        const float score = (part + sb2 + sbk) * 0.0625f + s_sc[r * 12 + s];
        const float nm = fmaxf(m, score);
        const float cc = __expf(m - nm);
        const float p = __expf(score - nm);
        d4 = d4 * cc + p;
        o0 = o0 * cc + p * ov.x; o1 = o1 * cc + p * ov.y;
        o2 = o2 * cc + p * ov.z; o3 = o3 * cc + p * ov.w;
        xa0 = xa0 * cc + p * xa; xa1 = xa1 * cc + p * xc;
        m = nm;
      }
      const float sn = s_sc[r * 12 + 5] * 0.0625f;
      const float M2 = fmaxf(m, sn);
      const float eM = __expf(m - M2), eN = __expf(sn - M2);
      const float invD = 1.f / (d4 * eM + eN);
      const float scl = eM * invD;
      ob[rr][0] = o0 * scl; ob[rr][1] = o1 * scl; ob[rr][2] = o2 * scl; ob[rr][3] = o3 * scl;
      xbr[rr][0] = xa0 * scl; xbr[rr][1] = xa1 * scl;
      wbar[rr] = d4 * eM * invD;
      w4r[rr] = eN * invD;
    }
    __syncthreads();  // everyone done reading s_x2/s_qk2 before overwrite
    float* s_obar = s_x2;
    float* s_x2b = s_x2 + 4096;
#pragma unroll
    for (int rr = 0; rr < 4; ++rr) {
      const int r = wv * 4 + rr;
      float4 o4;
      o4.x = ob[rr][0]; o4.y = ob[rr][1]; o4.z = ob[rr][2]; o4.w = ob[rr][3];
      st4(s_obar + r * 256 + lane * 4, o4);
      s_x2b[r * 128 + lane * 2] = xbr[rr][0];
      s_x2b[r * 128 + lane * 2 + 1] = xbr[rr][1];
      if (lane == 0) {
        s_sc[r * 12 + 8] = wbar[rr];
        s_sc[r * 12 + 9] = w4r[rr];
      }
    }
  }
  __syncthreads();

  // ---- ph5: fused = Wv obar + Wv2 x2b + Wbar*vb2p + w4*nv -> s_qk region --
  {
    float acc[16];
#pragma unroll
    for (int i = 0; i < 16; ++i) acc[i] = 0.f;
    mv_acc<16, 256, 256, 4>(s_x2, W + OFF_MTV, acc);
    mv_acc<16, 128, 256, 4>(s_x2 + 4096, W + OFF_MTV2, acc);
    const int tcol = t & 63, trg = t >> 6;
#pragma unroll
    for (int rr = 0; rr < 4; ++rr) {
      const int r = trg * 4 + rr;
      const float wb = s_sc[r * 12 + 8], w4v = s_sc[r * 12 + 9];
#pragma unroll
      for (int c = 0; c < 4; ++c) {
        const int col = tcol * 4 + c;
        s_qk[r * 256 + col] = acc[rr * 4 + c] + wb * W[OFF_VB2P + col] + w4v * nv[col];
      }
    }
  }
  __syncthreads();

  // ---- ph5b: LN stats ------------------------------------------------------
  {
    const int wv = t >> 6, lane = t & 63;
#pragma unroll
    for (int rr = 0; rr < 4; ++rr) {
      const int r = wv * 4 + rr;
      const float4 fv = ld4(s_qk + r * 256 + lane * 4);
      float sum = fv.x + fv.y + fv.z + fv.w;
      float sq = fv.x * fv.x + fv.y * fv.y + fv.z * fv.z + fv.w * fv.w;
      sum += __shfl_xor(sum, 32, 64); sq += __shfl_xor(sq, 32, 64);
      sum += __shfl_xor(sum, 16, 64); sq += __shfl_xor(sq, 16, 64);
      sum += __shfl_xor(sum, 8, 64);  sq += __shfl_xor(sq, 8, 64);
      sum += __shfl_xor(sum, 4, 64);  sq += __shfl_xor(sq, 4, 64);
      sum += __shfl_xor(sum, 2, 64);  sq += __shfl_xor(sq, 2, 64);
      sum += __shfl_xor(sum, 1, 64);  sq += __shfl_xor(sq, 1, 64);
      if (lane == 0) {
        const float mu = sum * (1.f / 256.f);
        const float var = sq * (1.f / 256.f) - mu * mu;
        s_sc[r * 12 + 10] = mu;
        s_sc[r * 12 + 11] = rsqrtf(var + 1e-5f);
      }
    }
  }

  // ---- ph6: gate = sigmoid(Wg1 h + Wg2 fused + bg) -> s_x2 region ---------
  {
    float acc[16];
#pragma unroll
    for (int i = 0; i < 16; ++i) acc[i] = 0.f;
    mv_acc<16, 256, 256, 4>(s_h, W + OFF_MTG1, acc);
    mv_acc<16, 256, 256, 4>(s_qk, W + OFF_MTG2, acc);
    const int tcol = t & 63, trg = t >> 6;
#pragma unroll
    for (int rr = 0; rr < 4; ++rr) {
      const int r = trg * 4 + rr;
#pragma unroll
      for (int c = 0; c < 4; ++c) {
        const int col = tcol * 4 + c;
        const float z = acc[rr * 4 + c] + bg[col];
        s_x2[r * 256 + col] = 1.f / (1.f + __expf(-z));
      }
    }
  }
  __syncthreads();

  // ---- ph7: out = h + gate*any_real * ((fused-mu)*inv*lnw + lnb) ----------
#pragma unroll
  for (int i = 0; i < Tr; ++i) {
    const float mu = s_sc[i * 12 + 10], inv = s_sc[i * 12 + 11], ar = s_sc[i * 12 + 7];
    const float f = s_qk[i * 256 + t];
    const float g = s_x2[i * 256 + t] * ar;
    const float upd = (f - mu) * inv * lnw[t] + lnb[t];
    out[(row0 + i) * 256 + t] = s_h[i * 256 + t] + g * upd;
  }
}

extern "C" void kernel_launch(void* const* d_in, const int* in_sizes, int n_in, void* d_out,
                              int out_size, void* d_ws, size_t ws_size, hipStream_t stream) {
  const float* h = (const float*)d_in[0];
  const float* obs = (const float*)d_in[1];
  const float* st = (const float*)d_in[2];
  const void* vd = d_in[3];
  const float* Wq = (const float*)d_in[4];
  const float* bq = (const float*)d_in[5];
  const float* Wk = (const float*)d_in[6];
  const float* bk = (const float*)d_in[7];
  const float* Wv = (const float*)d_in[8];
  const float* bv = (const float*)d_in[9];
  const float* nk = (const float*)d_in[10];
  const float* nv = (const float*)d_in[11];
  const float* w0 = (const float*)d_in[12];
  const float* b0 = (const float*)d_in[13];
  const float* w1 = (const float*)d_in[14];
  const float* b1 = (const float*)d_in[15];
  const float* w2 = (const float*)d_in[16];
  const float* b2 = (const float*)d_in[17];
  const float* Wg = (const float*)d_in[18];
  const float* bg = (const float*)d_in[19];
  const float* lnw = (const float*)d_in[20];
  const float* lnb = (const float*)d_in[21];
  float* out = (float*)d_out;
  float* W = (float*)d_ws;
  const int L = in_sizes[0] / 256;

  k_flag<<<1, 256, 0, stream>>>((const unsigned int*)vd, L, (int*)d_ws);
  k_prep<<<1025, 256, 0, stream>>>(Wq, bq, Wk, bk, Wv, bv, nk, w1, w2, b2, Wg, W);
  const size_t smem = 18688 * sizeof(float);
  k_main<<<L / Tr, 256, smem, stream>>>(h, obs, st, vd, w0, b0, b1, w2, b2, bg, lnw, lnb, nv, W,
                                        (const int*)d_ws, out);
}

// Round 2
// 500.940 us; speedup vs baseline: 1.9971x; 1.9971x over previous
//
#include <hip/hip_runtime.h>
#include <math.h>

// ---------------------------------------------------------------------------
// ObservationFusionModule — MFMA bf16 version.
//   qk   = (Wk^T Wq) h + Wk^T bq                       [QK gemm, K=256 N=256]
//   x2_s = relu(w1 @ relu(w0*log1p(st)+b0) + b1)       [X2 gemm, M=64 K=128 N=128]
//   qk2  = w2^T qk                                     [QK2 gemm, K=256 N=128]
//   score_s = (qk.obs_s + qk2.x2_s + h.NBK' + scc1)/16 + mask_s
//   null    = (h.NQ + scc2)/16          (NBK' = Wq^T(bk + Wk b2), NQ = Wq^T nk)
//   softmax online; obar = sum w_s obs_s ; x2b = sum w_s x2_s
//   fused = Wv obar + (Wv w2) x2b + wbar*(Wv b2 + bv) + w4*nv   [V + V2 gemms]
//   gate  = sigmoid(Wg [h;fused] + bg) * any_real      [G gemm, K=512 N=256]
//   out   = h + gate * LN(fused)
// All GEMM B-operands pre-packed to MFMA fragment layout (bf16) in ws by
// k_prep; A-operands live in XOR-swizzled bf16 LDS. Same k-packing convention
// on A and B makes the result independent of the HW intra-k permutation.
// ---------------------------------------------------------------------------

typedef __bf16 bf16x8 __attribute__((ext_vector_type(8)));
typedef float f32x4 __attribute__((ext_vector_type(4)));
typedef unsigned short u16;
typedef unsigned short u16x4 __attribute__((ext_vector_type(4)));
typedef unsigned short u16x2 __attribute__((ext_vector_type(2)));

constexpr int Tr = 16;  // rows per block

// ws float region
constexpr int OFF_BQK = 16;    // [256] Wk^T bq
constexpr int OFF_NBK = 272;   // [256] Wq^T (bk + Wk b2)
constexpr int OFF_NQ  = 528;   // [256] Wq^T null_key
constexpr int OFF_VB2P = 784;  // [256] Wv b2 + bv
constexpr int OFF_SCC = 1040;  // [0]=bq.(bk+Wk b2) [1]=bq.nk
// ws ushort fragment region starts at W + 2048 floats. [nt][kt][64][8] each.
constexpr size_t UOFF_QK  = 0;       // 16x8
constexpr size_t UOFF_X2W = 65536;   // 8x4
constexpr size_t UOFF_QK2 = 81920;   // 8x8
constexpr size_t UOFF_V   = 114688;  // 16x8
constexpr size_t UOFF_V2  = 180224;  // 16x4
constexpr size_t UOFF_G   = 212992;  // 16x16  (end 344064 ushorts)

// shared layout (ushort units)
constexpr int SH_H    = 0;      // [16][256] bf16 swz
constexpr int SH_QK   = 4096;   // [16][256] bf16 swz; later fusedA
constexpr int SH_QK2  = 8192;   // [16][128] bf16 unswz
constexpr int SH_OBAR = 10240;  // [16][256] bf16 swz
constexpr int SH_X2B  = 14336;  // [16][128] bf16 swz
constexpr int SH_GATE = 8192;   // [16][256] bf16 unswz (after obar/qk2 dead)
constexpr int SH_X2   = 16384;  // [64][128] bf16 swz; later fused f32 [16][256]
constexpr int SMEM_BYTES = 49152 + 1024;  // + s_sc[192] + s_x0[64]

__device__ __forceinline__ float4 ld4(const float* p) { return *reinterpret_cast<const float4*>(p); }
__device__ __forceinline__ u16 f2bf(float x) { __bf16 b = (__bf16)x; return __builtin_bit_cast(u16, b); }
__device__ __forceinline__ float bf2f(u16 u) {
  unsigned v = ((unsigned)u) << 16;
  return __builtin_bit_cast(float, v);
}
__device__ __forceinline__ f32x4 mfma16(bf16x8 a, bf16x8 b, f32x4 c) {
  return __builtin_amdgcn_mfma_f32_16x16x32_bf16(a, b, c, 0, 0, 0);
}
__device__ __forceinline__ bf16x8 ldA8(const u16* su, int base, int stride, int row, int kcol) {
  int off = (row * stride + kcol) ^ ((row & 7) << 3);
  return *reinterpret_cast<const bf16x8*>(su + base + off);
}
__device__ __forceinline__ bf16x8 ldB8(const u16* p, size_t off) {
  return *reinterpret_cast<const bf16x8*>(p + off);
}
__device__ __forceinline__ void stBF(u16* su, int base, int stride, int row, int col, float v) {
  int off = (row * stride + col) ^ ((row & 7) << 3);
  su[base + off] = f2bf(v);
}

// --- detect dtype of valid_stack (bool arrays can arrive as i32/u8/f32) ----
__global__ void k_flag(const unsigned int* __restrict__ v, int nwords, int* __restrict__ flag_out) {
  __shared__ int viol;
  if (threadIdx.x == 0) viol = 0;
  __syncthreads();
  int my = 0;
  for (int i = threadIdx.x; i < nwords; i += blockDim.x) {
    const unsigned int w = v[i];
    if (w > 1u) my |= 1;
    if (((w & 0xFFu) > 1u) || (((w >> 8) & 0xFFu) > 1u) || (((w >> 16) & 0xFFu) > 1u) ||
        ((w >> 24) > 1u))
      my |= 2;
  }
  atomicOr(&viol, my);
  __syncthreads();
  if (threadIdx.x == 0) {
    const int vv = viol;
    *flag_out = ((vv & 1) == 0) ? 0 : (((vv & 2) == 0) ? 1 : 2);  // 0=i32 1=u8 2=f32
  }
}

// --- weight prep: bf16 fragment-packed B matrices + f32 vectors ------------
__global__ void k_prep(const float* __restrict__ Wq, const float* __restrict__ bq,
                       const float* __restrict__ Wk, const float* __restrict__ bk,
                       const float* __restrict__ Wv, const float* __restrict__ bv,
                       const float* __restrict__ nk, const float* __restrict__ w1,
                       const float* __restrict__ w2, const float* __restrict__ b2,
                       const float* __restrict__ Wg, float* __restrict__ W) {
  const int b = blockIdx.x, t = threadIdx.x;
  u16* Wu = (u16*)(W + 2048);
  if (b < 672) {
    int gemm, nt, kt, KT;
    size_t ubase;
    if (b < 128)      { gemm = 0; KT = 8;  kt = b & 7;          nt = b >> 3;          ubase = UOFF_QK; }
    else if (b < 160) { gemm = 1; KT = 4;  kt = (b - 128) & 3;  nt = (b - 128) >> 2;  ubase = UOFF_X2W; }
    else if (b < 224) { gemm = 2; KT = 8;  kt = (b - 160) & 7;  nt = (b - 160) >> 3;  ubase = UOFF_QK2; }
    else if (b < 352) { gemm = 3; KT = 8;  kt = (b - 224) & 7;  nt = (b - 224) >> 3;  ubase = UOFF_V; }
    else if (b < 416) { gemm = 4; KT = 4;  kt = (b - 352) & 3;  nt = (b - 352) >> 2;  ubase = UOFF_V2; }
    else              { gemm = 5; KT = 16; kt = (b - 416) & 15; nt = (b - 416) >> 4;  ubase = UOFF_G; }
    for (int e = t; e < 512; e += 256) {
      const int l = e >> 3, j = e & 7;
      const int n = nt * 16 + (l & 15);
      const int k = kt * 32 + ((l >> 4) << 3) + j;
      float val;
      if (gemm == 0) {        // B[k][n] = sum_o Wk[o][n]*Wq[o][k]
        float a = 0.f;
        for (int o = 0; o < 256; ++o) a = fmaf(Wk[o * 256 + n], Wq[o * 256 + k], a);
        val = a;
      } else if (gemm == 1) { // w1[n][k]
        val = w1[n * 128 + k];
      } else if (gemm == 2) { // w2[k][n]
        val = w2[k * 128 + n];
      } else if (gemm == 3) { // Wv[n][k]
        val = Wv[n * 256 + k];
      } else if (gemm == 4) { // (Wv@w2)[n][k]
        float a = 0.f;
        for (int o = 0; o < 256; ++o) a = fmaf(Wv[n * 256 + o], w2[o * 128 + k], a);
        val = a;
      } else {                // Wg[n][k], k in [0,512)
        val = Wg[n * 512 + k];
      }
      Wu[ubase + (size_t)(nt * KT + kt) * 512 + e] = f2bf(val);
    }
  } else {  // vectors + scalars
    __shared__ float s_u[256];
    float a = 0.f;
    for (int hh = 0; hh < 256; ++hh) a = fmaf(Wk[t * 256 + hh], b2[hh], a);
    s_u[t] = a + bk[t];
    __syncthreads();
    float a1 = 0.f, a2 = 0.f, a3 = 0.f, a4 = 0.f;
    for (int o = 0; o < 256; ++o) {
      a1 = fmaf(Wq[o * 256 + t], s_u[o], a1);
      a2 = fmaf(Wq[o * 256 + t], nk[o], a2);
      a3 = fmaf(Wk[o * 256 + t], bq[o], a3);
      a4 = fmaf(Wv[t * 256 + o], b2[o], a4);
    }
    W[OFF_NBK + t] = a1;
    W[OFF_NQ + t] = a2;
    W[OFF_BQK + t] = a3;
    W[OFF_VB2P + t] = a4 + bv[t];
    if (t == 0) {
      float c1 = 0.f, c2 = 0.f;
      for (int o = 0; o < 256; ++o) {
        c1 = fmaf(bq[o], s_u[o], c1);
        c2 = fmaf(bq[o], nk[o], c2);
      }
      W[OFF_SCC] = c1;
      W[OFF_SCC + 1] = c2;
    }
  }
}

// --- main fused kernel ------------------------------------------------------
__launch_bounds__(256) __global__
void k_main(const float* __restrict__ h, const float* __restrict__ obs,
            const float* __restrict__ stal, const void* __restrict__ valid,
            const float* __restrict__ w0, const float* __restrict__ b0,
            const float* __restrict__ b1, const float* __restrict__ bg,
            const float* __restrict__ lnw, const float* __restrict__ lnb,
            const float* __restrict__ nv, const float* __restrict__ W,
            const int* __restrict__ flagp, float* __restrict__ out) {
  extern __shared__ char smraw[];
  u16* su = (u16*)smraw;
  float* s_sc = (float*)(smraw + 49152);  // [16][12]
  float* s_x0 = s_sc + 192;               // [64]
  float* sf = (float*)(su + SH_X2);       // fused f32 [16][256] (aliases s_x2)
  const u16* Wu = (const u16*)(W + 2048);
  const int t = threadIdx.x;
  const int lane = t & 63, wv = t >> 6;
  const int l16 = lane & 15, g = lane >> 4;
  const int row0 = blockIdx.x * Tr;
  const int mode = *flagp;

  // ---- ph0: stage h -> bf16 swz LDS; masks/x0/any_real --------------------
#pragma unroll
  for (int i = 0; i < Tr; ++i) {
    const float v = h[(size_t)(row0 + i) * 256 + t];
    su[SH_H + ((i * 256 + t) ^ ((i & 7) << 3))] = f2bf(v);
  }
  if (t < 64) {
    const int r = t >> 2, s = t & 3;
    const int idx = (row0 + r) * 4 + s;
    bool vb;
    if (mode == 0) vb = ((const int*)valid)[idx] != 0;
    else if (mode == 1) vb = ((const unsigned char*)valid)[idx] != 0;
    else vb = ((const float*)valid)[idx] != 0.f;
    s_sc[r * 12 + s] = vb ? 0.f : -5.f;
    s_x0[t] = log1pf(stal[idx]);
  } else if (t < 80) {
    const int r = t - 64;
    const int base = (row0 + r) * 4;
    bool any = false;
    for (int s = 0; s < 4; ++s) {
      bool vb;
      if (mode == 0) vb = ((const int*)valid)[base + s] != 0;
      else if (mode == 1) vb = ((const unsigned char*)valid)[base + s] != 0;
      else vb = ((const float*)valid)[base + s] != 0.f;
      any |= vb;
    }
    s_sc[r * 12 + 7] = any ? 1.f : 0.f;
  }
  __syncthreads();

  // ---- ph1: per-row score constants (all waves) + QK gemm ------------------
  {
    // 8 tasks/wave: task = (row off 0..3) x (which 0..1); 8 lanes per task.
    const int task = lane >> 3, sub = lane & 7;
    const int r = wv * 4 + (task >> 1);
    const int which = task & 1;
    const float* vecp = which ? (W + OFF_NQ) : (W + OFF_NBK);
    float acc = 0.f;
    const int c0 = sub * 32;
    for (int c = c0; c < c0 + 32; ++c) {
      const int off = (r * 256 + c) ^ ((r & 7) << 3);
      acc = fmaf(bf2f(su[SH_H + off]), vecp[c], acc);
    }
    acc += __shfl_xor(acc, 1, 64);
    acc += __shfl_xor(acc, 2, 64);
    acc += __shfl_xor(acc, 4, 64);
    if (sub == 0) s_sc[r * 12 + 4 + which] = acc + W[OFF_SCC + which];
  }
  {
    f32x4 acc[4] = {{0.f, 0.f, 0.f, 0.f}, {0.f, 0.f, 0.f, 0.f},
                    {0.f, 0.f, 0.f, 0.f}, {0.f, 0.f, 0.f, 0.f}};
#pragma unroll
    for (int kt = 0; kt < 8; ++kt) {
      const bf16x8 a = ldA8(su, SH_H, 256, l16, kt * 32 + g * 8);
#pragma unroll
      for (int n4 = 0; n4 < 4; ++n4) {
        const int nt = wv * 4 + n4;
        const bf16x8 b = ldB8(Wu, UOFF_QK + (size_t)((nt * 8 + kt) * 64 + lane) * 8);
        acc[n4] = mfma16(a, b, acc[n4]);
      }
    }
#pragma unroll
    for (int n4 = 0; n4 < 4; ++n4) {
      const int col = (wv * 4 + n4) * 16 + l16;
      const float bqk = W[OFF_BQK + col];
#pragma unroll
      for (int reg = 0; reg < 4; ++reg) stBF(su, SH_QK, 256, g * 4 + reg, col, acc[n4][reg] + bqk);
    }
  }
  __syncthreads();

  // ---- ph2: X2 gemm (on-the-fly A) + QK2 gemm ------------------------------
  {
    const float x0r = s_x0[wv * 16 + l16];
    f32x4 acc[8] = {{0.f,0.f,0.f,0.f},{0.f,0.f,0.f,0.f},{0.f,0.f,0.f,0.f},{0.f,0.f,0.f,0.f},
                    {0.f,0.f,0.f,0.f},{0.f,0.f,0.f,0.f},{0.f,0.f,0.f,0.f},{0.f,0.f,0.f,0.f}};
#pragma unroll
    for (int kt = 0; kt < 4; ++kt) {
      const int k0 = kt * 32 + g * 8;
      const float4 wa = ld4(w0 + k0), wb = ld4(w0 + k0 + 4);
      const float4 ba = ld4(b0 + k0), bb = ld4(b0 + k0 + 4);
      bf16x8 a;
      a[0] = (__bf16)fmaxf(fmaf(wa.x, x0r, ba.x), 0.f);
      a[1] = (__bf16)fmaxf(fmaf(wa.y, x0r, ba.y), 0.f);
      a[2] = (__bf16)fmaxf(fmaf(wa.z, x0r, ba.z), 0.f);
      a[3] = (__bf16)fmaxf(fmaf(wa.w, x0r, ba.w), 0.f);
      a[4] = (__bf16)fmaxf(fmaf(wb.x, x0r, bb.x), 0.f);
      a[5] = (__bf16)fmaxf(fmaf(wb.y, x0r, bb.y), 0.f);
      a[6] = (__bf16)fmaxf(fmaf(wb.z, x0r, bb.z), 0.f);
      a[7] = (__bf16)fmaxf(fmaf(wb.w, x0r, bb.w), 0.f);
#pragma unroll
      for (int nt = 0; nt < 8; ++nt) {
        const bf16x8 b = ldB8(Wu, UOFF_X2W + (size_t)((nt * 4 + kt) * 64 + lane) * 8);
        acc[nt] = mfma16(a, b, acc[nt]);
      }
    }
#pragma unroll
    for (int nt = 0; nt < 8; ++nt) {
      const int col = nt * 16 + l16;
      const float b1c = b1[col];
#pragma unroll
      for (int reg = 0; reg < 4; ++reg) {
        const int row = wv * 16 + g * 4 + reg;
        stBF(su, SH_X2, 128, row, col, fmaxf(acc[nt][reg] + b1c, 0.f));
      }
    }
  }
  {
    f32x4 acc[2] = {{0.f, 0.f, 0.f, 0.f}, {0.f, 0.f, 0.f, 0.f}};
#pragma unroll
    for (int kt = 0; kt < 8; ++kt) {
      const bf16x8 a = ldA8(su, SH_QK, 256, l16, kt * 32 + g * 8);
#pragma unroll
      for (int n2 = 0; n2 < 2; ++n2) {
        const int nt = wv * 2 + n2;
        const bf16x8 b = ldB8(Wu, UOFF_QK2 + (size_t)((nt * 8 + kt) * 64 + lane) * 8);
        acc[n2] = mfma16(a, b, acc[n2]);
      }
    }
#pragma unroll
    for (int n2 = 0; n2 < 2; ++n2) {
      const int col = (wv * 2 + n2) * 16 + l16;
#pragma unroll
      for (int reg = 0; reg < 4; ++reg)
        su[SH_QK2 + (g * 4 + reg) * 128 + col] = f2bf(acc[n2][reg]);
    }
  }
  __syncthreads();

  // ---- ph4: stream obs once; online softmax; obar/x2b ---------------------
  {
    float obr[4][4], x2br[4][2], wbar[4], w4r[4];
#pragma unroll
    for (int rr = 0; rr < 4; ++rr) {
      const int r = wv * 4 + rr;
      const size_t l = row0 + r;
      const int qoff = (r * 256 + lane * 4) ^ ((r & 7) << 3);
      const u16x4 qv4 = *reinterpret_cast<const u16x4*>(su + SH_QK + qoff);
      const float q0 = bf2f(qv4[0]), q1 = bf2f(qv4[1]), q2 = bf2f(qv4[2]), q3 = bf2f(qv4[3]);
      const float q2a = bf2f(su[SH_QK2 + r * 128 + lane * 2]);
      const float q2b = bf2f(su[SH_QK2 + r * 128 + lane * 2 + 1]);
      const float sbk = s_sc[r * 12 + 4];
      float m = -INFINITY, d4 = 0.f;
      float o0 = 0.f, o1 = 0.f, o2 = 0.f, o3 = 0.f, xa0 = 0.f, xa1 = 0.f;
#pragma unroll
      for (int s = 0; s < 4; ++s) {
        const float4 ov = ld4(obs + (l * 4 + s) * 256 + lane * 4);
        const int row2 = r * 4 + s;
        const int xoff = (row2 * 128 + lane * 2) ^ ((row2 & 7) << 3);
        const float xa = bf2f(su[SH_X2 + xoff]);
        const float xc = bf2f(su[SH_X2 + xoff + 1]);
        float part = q0 * ov.x + q1 * ov.y + q2 * ov.z + q3 * ov.w + q2a * xa + q2b * xc;
        part += __shfl_xor(part, 32, 64);
        part += __shfl_xor(part, 16, 64);
        part += __shfl_xor(part, 8, 64);
        part += __shfl_xor(part, 4, 64);
        part += __shfl_xor(part, 2, 64);
        part += __shfl_xor(part, 1, 64);
        const float score = (part + sbk) * 0.0625f + s_sc[r * 12 + s];
        const float nm = fmaxf(m, score);
        const float cc = __expf(m - nm);
        const float p = __expf(score - nm);
        d4 = d4 * cc + p;
        o0 = o0 * cc + p * ov.x; o1 = o1 * cc + p * ov.y;
        o2 = o2 * cc + p * ov.z; o3 = o3 * cc + p * ov.w;
        xa0 = xa0 * cc + p * xa; xa1 = xa1 * cc + p * xc;
        m = nm;
      }
      const float sn = s_sc[r * 12 + 5] * 0.0625f;
      const float M2 = fmaxf(m, sn);
      const float eM = __expf(m - M2), eN = __expf(sn - M2);
      const float invD = 1.f / (d4 * eM + eN);
      const float scl = eM * invD;
      obr[rr][0] = o0 * scl; obr[rr][1] = o1 * scl;
      obr[rr][2] = o2 * scl; obr[rr][3] = o3 * scl;
      x2br[rr][0] = xa0 * scl; x2br[rr][1] = xa1 * scl;
      wbar[rr] = d4 * eM * invD;
      w4r[rr] = eN * invD;
    }
    __syncthreads();  // all ph4 reads of s_qk/s_qk2/s_x2 done
#pragma unroll
    for (int rr = 0; rr < 4; ++rr) {
      const int r = wv * 4 + rr;
      const int ooff = (r * 256 + lane * 4) ^ ((r & 7) << 3);
      u16x4 o4;
      o4[0] = f2bf(obr[rr][0]); o4[1] = f2bf(obr[rr][1]);
      o4[2] = f2bf(obr[rr][2]); o4[3] = f2bf(obr[rr][3]);
      *reinterpret_cast<u16x4*>(su + SH_OBAR + ooff) = o4;
      const int xoff = (r * 128 + lane * 2) ^ ((r & 7) << 3);
      u16x2 x2;
      x2[0] = f2bf(x2br[rr][0]); x2[1] = f2bf(x2br[rr][1]);
      *reinterpret_cast<u16x2*>(su + SH_X2B + xoff) = x2;
      if (lane == 0) {
        s_sc[r * 12 + 8] = wbar[rr];
        s_sc[r * 12 + 9] = w4r[rr];
      }
    }
  }
  __syncthreads();

  // ---- ph5: fused = V(obar) + V2(x2b) + wbar*vb2p + w4*nv ------------------
  {
    f32x4 acc[4] = {{0.f, 0.f, 0.f, 0.f}, {0.f, 0.f, 0.f, 0.f},
                    {0.f, 0.f, 0.f, 0.f}, {0.f, 0.f, 0.f, 0.f}};
#pragma unroll
    for (int kt = 0; kt < 8; ++kt) {
      const bf16x8 a = ldA8(su, SH_OBAR, 256, l16, kt * 32 + g * 8);
#pragma unroll
      for (int n4 = 0; n4 < 4; ++n4) {
        const int nt = wv * 4 + n4;
        const bf16x8 b = ldB8(Wu, UOFF_V + (size_t)((nt * 8 + kt) * 64 + lane) * 8);
        acc[n4] = mfma16(a, b, acc[n4]);
      }
    }
#pragma unroll
    for (int kt = 0; kt < 4; ++kt) {
      const bf16x8 a = ldA8(su, SH_X2B, 128, l16, kt * 32 + g * 8);
#pragma unroll
      for (int n4 = 0; n4 < 4; ++n4) {
        const int nt = wv * 4 + n4;
        const bf16x8 b = ldB8(Wu, UOFF_V2 + (size_t)((nt * 4 + kt) * 64 + lane) * 8);
        acc[n4] = mfma16(a, b, acc[n4]);
      }
    }
#pragma unroll
    for (int n4 = 0; n4 < 4; ++n4) {
      const int col = (wv * 4 + n4) * 16 + l16;
      const float vb = W[OFF_VB2P + col];
      const float nvc = nv[col];
#pragma unroll
      for (int reg = 0; reg < 4; ++reg) {
        const int row = g * 4 + reg;
        const float f = acc[n4][reg] + s_sc[row * 12 + 8] * vb + s_sc[row * 12 + 9] * nvc;
        sf[row * 256 + col] = f;                 // f32 for LN + epilogue
        stBF(su, SH_QK, 256, row, col, f);       // bf16 A for gate gemm
      }
    }
  }
  __syncthreads();

  // ---- ph6: LN stats + gate gemm ------------------------------------------
  {
#pragma unroll
    for (int rr = 0; rr < 4; ++rr) {
      const int r = wv * 4 + rr;
      const float4 fv = ld4(sf + r * 256 + lane * 4);
      float sum = fv.x + fv.y + fv.z + fv.w;
      float sq = fv.x * fv.x + fv.y * fv.y + fv.z * fv.z + fv.w * fv.w;
      sum += __shfl_xor(sum, 32, 64); sq += __shfl_xor(sq, 32, 64);
      sum += __shfl_xor(sum, 16, 64); sq += __shfl_xor(sq, 16, 64);
      sum += __shfl_xor(sum, 8, 64);  sq += __shfl_xor(sq, 8, 64);
      sum += __shfl_xor(sum, 4, 64);  sq += __shfl_xor(sq, 4, 64);
      sum += __shfl_xor(sum, 2, 64);  sq += __shfl_xor(sq, 2, 64);
      sum += __shfl_xor(sum, 1, 64);  sq += __shfl_xor(sq, 1, 64);
      if (lane == 0) {
        const float mu = sum * (1.f / 256.f);
        const float var = sq * (1.f / 256.f) - mu * mu;
        s_sc[r * 12 + 10] = mu;
        s_sc[r * 12 + 11] = rsqrtf(var + 1e-5f);
      }
    }
  }
  {
    f32x4 acc[4] = {{0.f, 0.f, 0.f, 0.f}, {0.f, 0.f, 0.f, 0.f},
                    {0.f, 0.f, 0.f, 0.f}, {0.f, 0.f, 0.f, 0.f}};
#pragma unroll
    for (int kt = 0; kt < 16; ++kt) {
      const bf16x8 a = (kt < 8) ? ldA8(su, SH_H, 256, l16, kt * 32 + g * 8)
                                : ldA8(su, SH_QK, 256, l16, (kt - 8) * 32 + g * 8);
#pragma unroll
      for (int n4 = 0; n4 < 4; ++n4) {
        const int nt = wv * 4 + n4;
        const bf16x8 b = ldB8(Wu, UOFF_G + (size_t)((nt * 16 + kt) * 64 + lane) * 8);
        acc[n4] = mfma16(a, b, acc[n4]);
      }
    }
#pragma unroll
    for (int n4 = 0; n4 < 4; ++n4) {
      const int col = (wv * 4 + n4) * 16 + l16;
      const float bgc = bg[col];
#pragma unroll
      for (int reg = 0; reg < 4; ++reg) {
        const int row = g * 4 + reg;
        const float z = acc[n4][reg] + bgc;
        su[SH_GATE + row * 256 + col] = f2bf(1.f / (1.f + __expf(-z)));
      }
    }
  }
  __syncthreads();

  // ---- ph7: out = h + gate*any_real*((fused-mu)*inv*lnw+lnb) --------------
#pragma unroll
  for (int i = 0; i < Tr; ++i) {
    const float mu = s_sc[i * 12 + 10], inv = s_sc[i * 12 + 11], ar = s_sc[i * 12 + 7];
    const float f = sf[i * 256 + t];
    const float gt = bf2f(su[SH_GATE + i * 256 + t]) * ar;
    const float upd = (f - mu) * inv * lnw[t] + lnb[t];
    out[(size_t)(row0 + i) * 256 + t] = h[(size_t)(row0 + i) * 256 + t] + gt * upd;
  }
}

extern "C" void kernel_launch(void* const* d_in, const int* in_sizes, int n_in, void* d_out,
                              int out_size, void* d_ws, size_t ws_size, hipStream_t stream) {
  const float* h = (const float*)d_in[0];
  const float* obs = (const float*)d_in[1];
  const float* st = (const float*)d_in[2];
  const void* vd = d_in[3];
  const float* Wq = (const float*)d_in[4];
  const float* bq = (const float*)d_in[5];
  const float* Wk = (const float*)d_in[6];
  const float* bk = (const float*)d_in[7];
  const float* Wv = (const float*)d_in[8];
  const float* bv = (const float*)d_in[9];
  const float* nk = (const float*)d_in[10];
  const float* nv = (const float*)d_in[11];
  const float* w0 = (const float*)d_in[12];
  const float* b0 = (const float*)d_in[13];
  const float* w1 = (const float*)d_in[14];
  const float* b1 = (const float*)d_in[15];
  const float* w2 = (const float*)d_in[16];
  const float* b2 = (const float*)d_in[17];
  const float* Wg = (const float*)d_in[18];
  const float* bg = (const float*)d_in[19];
  const float* lnw = (const float*)d_in[20];
  const float* lnb = (const float*)d_in[21];
  float* out = (float*)d_out;
  float* W = (float*)d_ws;
  const int L = in_sizes[0] / 256;

  k_flag<<<1, 256, 0, stream>>>((const unsigned int*)vd, L, (int*)d_ws);
  k_prep<<<673, 256, 0, stream>>>(Wq, bq, Wk, bk, Wv, bv, nk, w1, w2, b2, Wg, W);
  k_main<<<L / Tr, 256, SMEM_BYTES, stream>>>(h, obs, st, vd, w0, b0, b1, bg, lnw, lnb, nv, W,
                                              (const int*)d_ws, out);
}